// Round 1
// baseline (336.406 us; speedup 1.0000x reference)
//
#include <hip/hip_runtime.h>
#include <stdint.h>

// out[t, :] = W[:, ids[t]]
// Bucket tokens by vocab window of 256, stream W coalesced exactly once
// through LDS tiles, emit per-token rows.
// Round 6: emit restructure. Old emit was stage(reg round-trip) -> full
// vmcnt(0)+syncthreads drain -> tiny emit -> block teardown, 16 waves/CU.
// New: global_load_lds staging (width 4 -- W rows are only 4B-aligned),
// persistent 4-subtile loop per block with double-buffered LDS, counted
// s_waitcnt vmcnt(N) + raw s_barrier (loads stay in flight across
// barriers), 512-thread blocks -> 32 waves/CU.
#define VOCAB   50257
#define DMODEL  1024
#define VWIN    256
#define NB      ((VOCAB + VWIN - 1) / VWIN)   // 197
#define DCHUNK  16                            // rows per subtile
#define NSUB    4                             // subtiles per block -> 64 d rows
#define HBLK    16                            // histogram/scatter blocks
#define NTOT    (NB * HBLK)                   // 3152 count slots

// ws layout (int32):
//   [0..4095]      counts[bucket*16 + blk]   (each slot written once; no memset)
//   [4096..8191]   start — exclusive scan of counts, NTOT+1 entries used
//   [8192..]       perm  — packed (id<<16)|t, grouped by bucket
#define WS_COUNT  0
#define WS_START  4096
#define WS_PERM   8192

typedef __attribute__((address_space(1))) const void* gas_ptr;
typedef __attribute__((address_space(3))) void*       las_ptr;

__global__ __launch_bounds__(256) void hist_kernel(
    const int* __restrict__ ids, int* __restrict__ ws, int n_tokens)
{
    __shared__ int h[NB];
    const int tid = threadIdx.x, blk = blockIdx.x;
    for (int i = tid; i < NB; i += 256) h[i] = 0;
    __syncthreads();
    const int per = (n_tokens + HBLK - 1) / HBLK;
    const int t0 = blk * per;
    const int t1 = min(n_tokens, t0 + per);
    for (int t = t0 + tid; t < t1; t += 256)
        atomicAdd(&h[ids[t] >> 8], 1);            // LDS atomic
    __syncthreads();
    for (int i = tid; i < NB; i += 256)
        ws[WS_COUNT + i * HBLK + blk] = h[i];     // plain store, slot unique
}

__global__ __launch_bounds__(256) void scan_kernel(int* __restrict__ ws)
{
    __shared__ int s[256];
    const int tid = threadIdx.x;
    const int CH = (NTOT + 255) / 256;            // 13
    const int base = tid * CH;
    int vals[(NTOT + 255) / 256];
    int sum = 0;
#pragma unroll
    for (int j = 0; j < CH; j++) {
        int idx = base + j;
        int v = (idx < NTOT) ? ws[WS_COUNT + idx] : 0;
        vals[j] = v; sum += v;
    }
    s[tid] = sum;
    __syncthreads();
    for (int off = 1; off < 256; off <<= 1) {
        int v = (tid >= off) ? s[tid - off] : 0;
        __syncthreads();
        s[tid] += v;
        __syncthreads();
    }
    int run = (tid > 0) ? s[tid - 1] : 0;         // exclusive prefix
#pragma unroll
    for (int j = 0; j < CH; j++) {
        int idx = base + j;
        if (idx < NTOT) ws[WS_START + idx] = run;
        run += vals[j];
    }
    if (tid == 255) ws[WS_START + NTOT] = run;    // total
}

__global__ __launch_bounds__(256) void scatter_kernel(
    const int* __restrict__ ids, int* __restrict__ ws, int n_tokens)
{
    __shared__ int cur[NB];
    const int tid = threadIdx.x, blk = blockIdx.x;
    for (int i = tid; i < NB; i += 256)
        cur[i] = ws[WS_START + i * HBLK + blk];   // this block's range starts
    __syncthreads();
    const int per = (n_tokens + HBLK - 1) / HBLK;
    const int t0 = blk * per;
    const int t1 = min(n_tokens, t0 + per);
    for (int t = t0 + tid; t < t1; t += 256) {
        int id = ids[t];
        int b  = id >> 8;
        int pos = atomicAdd(&cur[b], 1);          // LDS atomic
        ws[WS_PERM + pos] = (int)(((uint32_t)id << 16) | (uint32_t)t);
    }
}

// Block = (vwin, 64-row d-slab). 4 subtiles of 16x256, double-buffered.
// LDS 2*16*257*4 = 32.9 KB -> 4 blocks/CU; 512 thr -> 32 waves/CU.
__global__ __launch_bounds__(512) void emit_kernel(
    const float* __restrict__ W, const int* __restrict__ ws,
    float* __restrict__ out)
{
    __shared__ float tile[2][DCHUNK][VWIN + 1];

    const int vwin  = blockIdx.x;                 // 0..196
    const int dbase = blockIdx.y * (DCHUNK * NSUB); // 0..960 step 64
    const int v0    = vwin << 8;
    const int tid   = threadIdx.x;
    const int lane  = tid & 63;
    const int w     = tid >> 6;                   // wave 0..7

    const int begin = ws[WS_START + vwin * HBLK];
    const int end   = ws[WS_START + (vwin + 1) * HBLK];

    const int g = lane >> 2;                      // token slot 0..15
    const int j = lane & 3;                       // d-quad 0..3

    // emit one subtile: 16 tokens/wave-iter, 4 lanes x float4 per token
    auto emit_sub = [&](int buf, int k) {
        const float (*tb)[VWIN + 1] = tile[buf];
        const int dk = dbase + k * DCHUNK;
        for (int i = begin + w * 16; i < end; i += 8 * 16) {
            int idx = i + g;
            if (idx < end) {
                uint32_t packed = (uint32_t)ws[WS_PERM + idx];
                int t   = (int)(packed & 0xFFFFu);
                int col = (int)(packed >> 16) - v0;
                float4 v;
                v.x = tb[j * 4 + 0][col];
                v.y = tb[j * 4 + 1][col];
                v.z = tb[j * 4 + 2][col];
                v.w = tb[j * 4 + 3][col];
                *(float4*)(out + (size_t)t * DMODEL + dk + j * 4) = v;
            }
        }
    };

    if (vwin == NB - 1) {
        // last window: only 81 valid cols; guarded scalar staging, no async
        const int limit = VOCAB - v0;
        for (int k = 0; k < NSUB; ++k) {
            const int dk = dbase + k * DCHUNK;
            for (int e = tid; e < DCHUNK * VWIN; e += 512) {
                int r = e >> 8, c = e & 255;
                tile[0][r][c] = (c < limit)
                    ? W[(size_t)(dk + r) * VOCAB + v0 + c] : 0.0f;
            }
            __syncthreads();
            emit_sub(0, k);
            __syncthreads();
        }
        return;
    }

    // async stage of one subtile: each wave fills 2 rows, 4 quarter-row
    // global_load_lds each (width 4: W row base is only 4B-aligned).
    // LDS dest per load is wave-uniform row base (+q*256B); pad sits
    // between rows so the linear lane*4 destination never touches it.
    auto stage = [&](int buf, int k) {
        const int dk = dbase + k * DCHUNK;
#pragma unroll
        for (int r2 = 0; r2 < 2; ++r2) {
            const int row = w * 2 + r2;
            const float* gsrc = W + (size_t)(dk + row) * VOCAB + v0 + lane;
            float* ldst = &tile[buf][row][0];
#pragma unroll
            for (int q = 0; q < 4; ++q) {
                __builtin_amdgcn_global_load_lds(
                    (gas_ptr)(gsrc + q * 64), (las_ptr)(ldst + q * 64),
                    4, 0, 0);
            }
        }
    };

    stage(0, 0);                                  // prologue: 8 loads/wave
    int cur = 0;
#pragma unroll
    for (int k = 0; k < NSUB; ++k) {
        if (k + 1 < NSUB) {
            stage(cur ^ 1, k + 1);                // +8 loads -> 16 in flight
            // drain current subtile's 8 (oldest) + any emit stragglers;
            // keep next subtile's 8 in flight across the barrier
            asm volatile("s_waitcnt vmcnt(8)" ::: "memory");
        } else {
            asm volatile("s_waitcnt vmcnt(0)" ::: "memory");
        }
        __builtin_amdgcn_s_barrier();
        asm volatile("" ::: "memory");
        emit_sub(cur, k);
        asm volatile("" ::: "memory");
        __builtin_amdgcn_s_barrier();             // reads done before re-stage
        cur ^= 1;
    }
}

extern "C" void kernel_launch(void* const* d_in, const int* in_sizes, int n_in,
                              void* d_out, int out_size, void* d_ws, size_t ws_size,
                              hipStream_t stream) {
    const int*   ids = (const int*)d_in[0];    // [B*S] = 16384
    const float* W   = (const float*)d_in[1];  // [1024, 50257]
    float*       out = (float*)d_out;
    int*         ws  = (int*)d_ws;

    const int n_tokens = in_sizes[0];

    hist_kernel<<<HBLK, 256, 0, stream>>>(ids, ws, n_tokens);
    scan_kernel<<<1, 256, 0, stream>>>(ws);
    scatter_kernel<<<HBLK, 256, 0, stream>>>(ids, ws, n_tokens);

    dim3 grid(NB, DMODEL / (DCHUNK * NSUB));   // 197 x 16
    emit_kernel<<<grid, 512, 0, stream>>>(W, ws, out);
}